// Round 1
// baseline (113.375 us; speedup 1.0000x reference)
//
#include <hip/hip_runtime.h>

// Sinkhorn top-K collapsed to a per-row 1-D Newton solve.
// B=512 rows, N=4096 cols, K=256, eps=0.1.
// Math: t[n] = G0/G1 = exp((1-2*s[n]) * alpha), alpha = 1/(M*eps), M = global max cost.
// Fixed point: find rho with h(rho) = sum_n rho*t/(rho*t+1) = K  (concave, monotone).
// Then P1[n] = mu * w[n], P0[n] = mu * (1 - w[n]),  w = 1/(rho*t+1).
// Reference's 200 Sinkhorn iterations are machine-converged (Birkhoff contraction
// ~0.876^400 ~ e^-53), so the fixed point equals the reference output.

#define NROWS 512
#define NCOLS 4096
#define KSEL 256
#define EPSREG 0.1f
#define NEWTON_ITERS 32   // quadratic convergence; deliberate safety margin round 1

__device__ __forceinline__ float fastrcp(float x) {
#if __has_builtin(__builtin_amdgcn_rcpf)
    return __builtin_amdgcn_rcpf(x);
#else
    return 1.0f / x;
#endif
}

// ---------------- Kernel A: global max of max(s^2, (s-1)^2) ----------------
__global__ __launch_bounds__(256) void kmax_kernel(const float4* __restrict__ s4,
                                                   int* __restrict__ gmax) {
    int tid = blockIdx.x * 256 + threadIdx.x;  // 512*256 = 131072 threads
    float m = 0.f;
#pragma unroll
    for (int j = 0; j < 4; ++j) {
        float4 v = s4[tid + 131072 * j];       // 4 * 131072 = 524288 float4 = 2M floats
        m = fmaxf(m, fmaxf(v.x * v.x, (v.x - 1.f) * (v.x - 1.f)));
        m = fmaxf(m, fmaxf(v.y * v.y, (v.y - 1.f) * (v.y - 1.f)));
        m = fmaxf(m, fmaxf(v.z * v.z, (v.z - 1.f) * (v.z - 1.f)));
        m = fmaxf(m, fmaxf(v.w * v.w, (v.w - 1.f) * (v.w - 1.f)));
    }
#pragma unroll
    for (int off = 32; off >= 1; off >>= 1)
        m = fmaxf(m, __shfl_xor(m, off, 64));
    if ((threadIdx.x & 63) == 0)
        atomicMax(gmax, __float_as_int(m));    // all values >= 0.25, int-ordering valid
}

// ---------------- Kernel B: per-row Newton solve + write P ----------------
__global__ __launch_bounds__(256) void sinkhorn_kernel(const float* __restrict__ s,
                                                       const float* __restrict__ ws,
                                                       float* __restrict__ out) {
    const int b   = blockIdx.x;
    const int tid = threadIdx.x;
    const int wv  = tid >> 6;          // wave id 0..3
    const int ln  = tid & 63;

    __shared__ float lds[2][8];        // ping-pong, [phase][wave*2 + {A,Q}]

    const float M     = ws[0];
    const float alpha = 1.0f / (M * EPSREG);
    const float c2    = -2.0f * alpha;

    const float4* srow = (const float4*)(s + (size_t)b * NCOLS);

    float t[16];
    float sumt = 0.f;
#pragma unroll
    for (int j = 0; j < 4; ++j) {
        float4 v = srow[tid + 256 * j];
        float xs[4] = {v.x, v.y, v.z, v.w};
#pragma unroll
        for (int e = 0; e < 4; ++e) {
            float tt = __expf(fmaf(xs[e], c2, alpha));   // exp((1-2x)*alpha)
            t[4 * j + e] = tt;
            sumt += tt;
        }
    }

    // block-reduce sum(t)
#pragma unroll
    for (int off = 32; off >= 1; off >>= 1)
        sumt += __shfl_xor(sumt, off, 64);
    if (ln == 0) lds[0][wv] = sumt;
    __syncthreads();
    sumt = lds[0][0] + lds[0][1] + lds[0][2] + lds[0][3];
    __syncthreads();   // protect lds[0] before Newton iter 0 reuses it

    // rho0 = K / sum(t): h(rho0) < K strictly -> monotone Newton from below
    float rho = (float)KSEL / sumt;

#pragma unroll 1
    for (int it = 0; it < NEWTON_ITERS; ++it) {
        float a = 0.f, q = 0.f;
#pragma unroll
        for (int e = 0; e < 16; ++e) {
            float w = fastrcp(fmaf(rho, t[e], 1.0f));
            a += w;
            q = fmaf(w, w, q);
        }
#pragma unroll
        for (int off = 32; off >= 1; off >>= 1) {
            a += __shfl_xor(a, off, 64);
            q += __shfl_xor(q, off, 64);
        }
        const int ph = it & 1;
        if (ln == 0) { lds[ph][wv * 2] = a; lds[ph][wv * 2 + 1] = q; }
        __syncthreads();
        a = lds[ph][0] + lds[ph][2] + lds[ph][4] + lds[ph][6];
        q = lds[ph][1] + lds[ph][3] + lds[ph][5] + lds[ph][7];
        // h(rho) = N - A, h'(rho) = (A - Q)/rho ; Newton: rho += (K - N + A)*rho/(A - Q)
        rho += ((float)(KSEL - NCOLS) + a) * rho / (a - q);
    }

    // P0[n] = mu*(1-w), P1[n] = mu*w ; out layout [b, 2, n]
    const float MU = 1.0f / (float)NCOLS;
    float4* o0 = (float4*)(out + (size_t)b * 2 * NCOLS);
    float4* o1 = (float4*)(out + (size_t)b * 2 * NCOLS + NCOLS);
#pragma unroll
    for (int j = 0; j < 4; ++j) {
        float r0[4], r1[4];
#pragma unroll
        for (int e = 0; e < 4; ++e) {
            float w  = fastrcp(fmaf(rho, t[4 * j + e], 1.0f));
            float p1 = MU * w;
            r1[e] = p1;
            r0[e] = MU - p1;
        }
        o0[tid + 256 * j] = make_float4(r0[0], r0[1], r0[2], r0[3]);
        o1[tid + 256 * j] = make_float4(r1[0], r1[1], r1[2], r1[3]);
    }
}

extern "C" void kernel_launch(void* const* d_in, const int* in_sizes, int n_in,
                              void* d_out, int out_size, void* d_ws, size_t ws_size,
                              hipStream_t stream) {
    const float* scores = (const float*)d_in[0];
    float* out = (float*)d_out;

    hipMemsetAsync(d_ws, 0, 4, stream);   // capture-safe async memset
    hipLaunchKernelGGL(kmax_kernel, dim3(512), dim3(256), 0, stream,
                       (const float4*)scores, (int*)d_ws);
    hipLaunchKernelGGL(sinkhorn_kernel, dim3(NROWS), dim3(256), 0, stream,
                       scores, (const float*)d_ws, out);
}

// Round 2
// 76.031 us; speedup vs baseline: 1.4912x; 1.4912x over previous
//
#include <hip/hip_runtime.h>

// Sinkhorn top-K collapsed to a per-row 1-D Newton solve.
// B=512 rows, N=4096 cols, K=256, eps=0.1.
// t[n] = exp((1-2*s[n]) * alpha), alpha = 1/(M*eps), M = global max of (s-anchor)^2.
// Solve h(rho) = sum_n rho*t/(rho*t+1) = K (concave, monotone; Newton from below).
// P1[n] = mu/(rho*t+1) -> wait: P1 = mu*w with w = 1/(rho*t+1)?  Derivation:
//   P0[n] = mu*(1 - w[n]), P1[n] = mu*w[n], w = 1/(rho*t + 1).
// R2 changes: memset node removed (block-max array instead of atomicMax),
// Newton 32 -> 12 iters (converged by ~7; absmax was 9.5e-7 at 32).

#define NROWS 512
#define NCOLS 4096
#define KSEL 256
#define EPSREG 0.1f
#define NEWTON_ITERS 12

__device__ __forceinline__ float fastrcp(float x) {
#if __has_builtin(__builtin_amdgcn_rcpf)
    return __builtin_amdgcn_rcpf(x);
#else
    return 1.0f / x;
#endif
}

// ---- Kernel A: per-block max of max(s^2,(s-1)^2); 256 blocks, no atomics ----
__global__ __launch_bounds__(256) void kmax_kernel(const float4* __restrict__ s4,
                                                   float* __restrict__ blkmax) {
    const int tid = blockIdx.x * 256 + threadIdx.x;   // 65536 threads
    float m = 0.f;
#pragma unroll
    for (int j = 0; j < 8; ++j) {                     // 65536*8 = 524288 float4 = 2M floats
        float4 v = s4[tid + 65536 * j];
        m = fmaxf(m, fmaxf(v.x * v.x, (v.x - 1.f) * (v.x - 1.f)));
        m = fmaxf(m, fmaxf(v.y * v.y, (v.y - 1.f) * (v.y - 1.f)));
        m = fmaxf(m, fmaxf(v.z * v.z, (v.z - 1.f) * (v.z - 1.f)));
        m = fmaxf(m, fmaxf(v.w * v.w, (v.w - 1.f) * (v.w - 1.f)));
    }
#pragma unroll
    for (int off = 32; off >= 1; off >>= 1)
        m = fmaxf(m, __shfl_xor(m, off, 64));
    __shared__ float wmax[4];
    if ((threadIdx.x & 63) == 0) wmax[threadIdx.x >> 6] = m;
    __syncthreads();
    if (threadIdx.x == 0)
        blkmax[blockIdx.x] = fmaxf(fmaxf(wmax[0], wmax[1]), fmaxf(wmax[2], wmax[3]));
}

// ---- Kernel B: per-row Newton solve + write P; 512 blocks x 256 thr ----
__global__ __launch_bounds__(256) void sinkhorn_kernel(const float* __restrict__ s,
                                                       const float* __restrict__ blkmax,
                                                       float* __restrict__ out) {
    const int b   = blockIdx.x;
    const int tid = threadIdx.x;
    const int wv  = tid >> 6;
    const int ln  = tid & 63;

    __shared__ float ldsm[4];
    __shared__ float lds[2][8];   // Newton ping-pong [phase][wave*2 + {A,Q}]

    // ---- global max from 256 block maxes (1 value/thread, coalesced, L2-hot)
    float m = blkmax[tid];
#pragma unroll
    for (int off = 32; off >= 1; off >>= 1)
        m = fmaxf(m, __shfl_xor(m, off, 64));
    if (ln == 0) ldsm[wv] = m;

    // ---- row load can be issued independently of M
    const float4* srow = (const float4*)(s + (size_t)b * NCOLS);
    float4 v[4];
#pragma unroll
    for (int j = 0; j < 4; ++j) v[j] = srow[tid + 256 * j];

    __syncthreads();              // barrier 1: ldsm visible
    const float M     = fmaxf(fmaxf(ldsm[0], ldsm[1]), fmaxf(ldsm[2], ldsm[3]));
    const float alpha = 1.0f / (M * EPSREG);
    const float c2    = -2.0f * alpha;

    float t[16];
    float sumt = 0.f;
#pragma unroll
    for (int j = 0; j < 4; ++j) {
        float xs[4] = {v[j].x, v[j].y, v[j].z, v[j].w};
#pragma unroll
        for (int e = 0; e < 4; ++e) {
            float tt = __expf(fmaf(xs[e], c2, alpha));   // exp((1-2x)*alpha)
            t[4 * j + e] = tt;
            sumt += tt;
        }
    }

#pragma unroll
    for (int off = 32; off >= 1; off >>= 1)
        sumt += __shfl_xor(sumt, off, 64);
    if (ln == 0) lds[1][wv * 2] = sumt;   // use phase-1 slots: iter0 writes phase 0
    __syncthreads();              // barrier 2
    sumt = lds[1][0] + lds[1][2] + lds[1][4] + lds[1][6];

    // rho0 = K/sum(t): h(rho0) < K strictly -> monotone Newton from below
    float rho = (float)KSEL / sumt;

#pragma unroll 1
    for (int it = 0; it < NEWTON_ITERS; ++it) {
        float a = 0.f, q = 0.f;
#pragma unroll
        for (int e = 0; e < 16; ++e) {
            float w = fastrcp(fmaf(rho, t[e], 1.0f));
            a += w;
            q = fmaf(w, w, q);
        }
#pragma unroll
        for (int off = 32; off >= 1; off >>= 1) {
            a += __shfl_xor(a, off, 64);
            q += __shfl_xor(q, off, 64);
        }
        const int ph = it & 1;
        if (ln == 0) { lds[ph][wv * 2] = a; lds[ph][wv * 2 + 1] = q; }
        __syncthreads();          // one barrier/iter; ping-pong handles WAR
        a = lds[ph][0] + lds[ph][2] + lds[ph][4] + lds[ph][6];
        q = lds[ph][1] + lds[ph][3] + lds[ph][5] + lds[ph][7];
        // h(rho) = N - A, h'(rho) = (A - Q)/rho
        rho += ((float)(KSEL - NCOLS) + a) * rho / (a - q);
    }

    // P0[n] = mu*(1-w), P1[n] = mu*w ; out layout [b, 2, n]
    const float MU = 1.0f / (float)NCOLS;
    float4* o0 = (float4*)(out + (size_t)b * 2 * NCOLS);
    float4* o1 = (float4*)(out + (size_t)b * 2 * NCOLS + NCOLS);
#pragma unroll
    for (int j = 0; j < 4; ++j) {
        float r0[4], r1[4];
#pragma unroll
        for (int e = 0; e < 4; ++e) {
            float w  = fastrcp(fmaf(rho, t[4 * j + e], 1.0f));
            float p1 = MU * w;
            r1[e] = p1;
            r0[e] = MU - p1;
        }
        o0[tid + 256 * j] = make_float4(r0[0], r0[1], r0[2], r0[3]);
        o1[tid + 256 * j] = make_float4(r1[0], r1[1], r1[2], r1[3]);
    }
}

extern "C" void kernel_launch(void* const* d_in, const int* in_sizes, int n_in,
                              void* d_out, int out_size, void* d_ws, size_t ws_size,
                              hipStream_t stream) {
    const float* scores = (const float*)d_in[0];
    float* out = (float*)d_out;
    float* blkmax = (float*)d_ws;   // 256 floats; every slot written, no init needed

    hipLaunchKernelGGL(kmax_kernel, dim3(256), dim3(256), 0, stream,
                       (const float4*)scores, blkmax);
    hipLaunchKernelGGL(sinkhorn_kernel, dim3(NROWS), dim3(256), 0, stream,
                       scores, blkmax, out);
}